// Round 5
// baseline (259.876 us; speedup 1.0000x reference)
//
#include <hip/hip_runtime.h>
#include <math.h>

// Problem constants (B=64, P=2, H=512, W=512)
#define HH 512
#define WW 512
#define BP 128                  // B*P pairs
#define PLANE (HH * WW)         // 262144 elems per (b,p) plane
#define SEG2 32                 // segments per pair
#define SEG_FLOATS 8192         // floats per segment (32 KB)
#define NPART2 (BP * SEG2)      // 4096 partial records per quantity

// ws float layout: [0,4096) sum, [4096,8192) sumx, [8192,12288) sumy,
// [12288,16384) maxval ; ints at float offset [16384,20480) maxidx. 80 KiB.

// R9: nt + depth-4 register pipeline. R8 proved the 2.7 TB/s wall was
// Infinity-Cache allocate thrash (working set == 256 MiB IC): nt loads took
// dsnt_partial 99 -> ~77 us. Now delivered ~3.5 TB/s of a 6.3-6.9 ceiling
// (fillBuffer memsets measure 6.9). Remaining limiter: depth-2 rotation
// keeps only ~2 KB/wave in flight. Depth-4 named rotation (16 data VGPRs,
// fully static) doubles per-wave MLP; Little's law then saturates HBM at
// ~16 resident waves/CU.
typedef float f4 __attribute__((ext_vector_type(4)));

__global__ __launch_bounds__(256) void dsnt_partial(
    const float* __restrict__ inp, const float* __restrict__ tgt,
    float* __restrict__ wsf, int* __restrict__ wsi)
{
    const int tid  = threadIdx.x;
    const int blk  = blockIdx.x;
    const int lane = tid & 63, wid = tid >> 6;
    const float inv = 1.0f / 512.0f;

    __shared__ float rs[4], rsx[4], rsy[4], rmv[4];
    __shared__ int   rmi[4];

    const bool is_sm = (blk < NPART2);
    const int  b2    = is_sm ? blk : blk - NPART2;
    const int  pair  = b2 >> 5;
    const int  seg   = b2 & 31;
    const f4* __restrict__ gp =
        (const f4*)((is_sm ? inp : tgt) + (size_t)pair * PLANE + seg * SEG_FLOATS);
    const int segbase = seg * SEG_FLOATS;

    if (is_sm) {
        // ---- softmax partial sums, depth-4 nt pipeline ----
        float s = 0.0f, sx = 0.0f, sy = 0.0f;
#define SM_ACC(v, jj)                                                          \
        do {                                                                   \
            const int f = segbase + ((jj) * 256 + tid) * 4; /* %4==0 */        \
            const float yw  = (float)((f >> 9) + 1) * inv;                     \
            const float xw0 = (float)((f & 511) + 1) * inv;                    \
            const float e0 = __expf(v.x);                                      \
            const float e1 = __expf(v.y);                                      \
            const float e2 = __expf(v.z);                                      \
            const float e3 = __expf(v.w);                                      \
            const float es = e0 + e1 + e2 + e3;                                \
            s  += es;                                                          \
            sx += es * xw0 + inv * (e1 + 2.0f * e2 + 3.0f * e3);               \
            sy += es * yw;                                                     \
        } while (0)
        f4 c0 = __builtin_nontemporal_load(gp + 0 * 256 + tid);
        f4 c1 = __builtin_nontemporal_load(gp + 1 * 256 + tid);
        f4 c2 = __builtin_nontemporal_load(gp + 2 * 256 + tid);
        f4 c3 = __builtin_nontemporal_load(gp + 3 * 256 + tid);
        SM_ACC(c0, 0); c0 = __builtin_nontemporal_load(gp + 4 * 256 + tid);
        SM_ACC(c1, 1); c1 = __builtin_nontemporal_load(gp + 5 * 256 + tid);
        SM_ACC(c2, 2); c2 = __builtin_nontemporal_load(gp + 6 * 256 + tid);
        SM_ACC(c3, 3); c3 = __builtin_nontemporal_load(gp + 7 * 256 + tid);
        SM_ACC(c0, 4); SM_ACC(c1, 5); SM_ACC(c2, 6); SM_ACC(c3, 7);
#undef SM_ACC

#pragma unroll
        for (int off = 32; off > 0; off >>= 1) {
            s  += __shfl_down(s,  off, 64);
            sx += __shfl_down(sx, off, 64);
            sy += __shfl_down(sy, off, 64);
        }
        if (lane == 0) { rs[wid] = s; rsx[wid] = sx; rsy[wid] = sy; }
        __syncthreads();
        if (tid == 0) {
            float fs = rs[0], fsx = rsx[0], fsy = rsy[0];
#pragma unroll
            for (int k = 1; k < 4; ++k) { fs += rs[k]; fsx += rsx[k]; fsy += rsy[k]; }
            wsf[blk]              = fs;
            wsf[NPART2 + blk]     = fsx;
            wsf[2 * NPART2 + blk] = fsy;
        }
    } else {
        // ---- argmax partial over target, depth-4 nt pipeline ----
        float mv = -1.0f;
        int   mi = 0;
#define AM_ACC(v, jj)                                                          \
        do {                                                                   \
            const int f = segbase + ((jj) * 256 + tid) * 4;                    \
            if (v.x > mv) { mv = v.x; mi = f; }                                \
            if (v.y > mv) { mv = v.y; mi = f + 1; }                            \
            if (v.z > mv) { mv = v.z; mi = f + 2; }                            \
            if (v.w > mv) { mv = v.w; mi = f + 3; }                            \
        } while (0)
        f4 t0 = __builtin_nontemporal_load(gp + 0 * 256 + tid);
        f4 t1 = __builtin_nontemporal_load(gp + 1 * 256 + tid);
        f4 t2 = __builtin_nontemporal_load(gp + 2 * 256 + tid);
        f4 t3 = __builtin_nontemporal_load(gp + 3 * 256 + tid);
        AM_ACC(t0, 0); t0 = __builtin_nontemporal_load(gp + 4 * 256 + tid);
        AM_ACC(t1, 1); t1 = __builtin_nontemporal_load(gp + 5 * 256 + tid);
        AM_ACC(t2, 2); t2 = __builtin_nontemporal_load(gp + 6 * 256 + tid);
        AM_ACC(t3, 3); t3 = __builtin_nontemporal_load(gp + 7 * 256 + tid);
        AM_ACC(t0, 4); AM_ACC(t1, 5); AM_ACC(t2, 6); AM_ACC(t3, 7);
#undef AM_ACC

#pragma unroll
        for (int off = 32; off > 0; off >>= 1) {
            const float ov = __shfl_down(mv, off, 64);
            const int   oi = __shfl_down(mi, off, 64);
            if (ov > mv || (ov == mv && oi < mi)) { mv = ov; mi = oi; }
        }
        if (lane == 0) { rmv[wid] = mv; rmi[wid] = mi; }
        __syncthreads();
        if (tid == 0) {
            float fmv = rmv[0];
            int   fmi = rmi[0];
#pragma unroll
            for (int k = 1; k < 4; ++k)
                if (rmv[k] > fmv || (rmv[k] == fmv && rmi[k] < fmi)) { fmv = rmv[k]; fmi = rmi[k]; }
            wsf[3 * NPART2 + b2] = fmv;
            wsi[b2]              = fmi;
        }
    }
}

__global__ __launch_bounds__(128) void dsnt_finalize(
    const float* __restrict__ wsf, const int* __restrict__ wsi,
    float* __restrict__ out)
{
    __shared__ float px[BP], py[BP], tx[BP], ty[BP];
    __shared__ float wsum[2];
    const int tid = threadIdx.x; // 0..127, one pair per thread

    {
        float s = 0.0f, sx = 0.0f, sy = 0.0f, mv = -1.0f;
        int mi = 0;
#pragma unroll
        for (int k = 0; k < SEG2; ++k) {
            const int i = tid * SEG2 + k;  // segs in ascending index order
            s  += wsf[i];
            sx += wsf[NPART2 + i];
            sy += wsf[2 * NPART2 + i];
            const float v = wsf[3 * NPART2 + i];
            const int  ii = wsi[i];
            if (v > mv || (v == mv && ii < mi)) { mv = v; mi = ii; }
        }
        px[tid] = sx / s;
        py[tid] = sy / s;
        tx[tid] = (float)((mi & 511) + 1) * (1.0f / 512.0f);
        ty[tid] = (float)((mi >> 9) + 1) * (1.0f / 512.0f);
    }
    __syncthreads();

    float term = 0.0f;
    if (tid < 64) {
        const int b = tid;
        const float px0 = px[2 * b], px1 = px[2 * b + 1];
        const float py0 = py[2 * b], py1 = py[2 * b + 1];
        const float tx0 = tx[2 * b], tx1 = tx[2 * b + 1];
        const float ty0 = ty[2 * b], ty1 = ty[2 * b + 1];

        const float ed0 = sqrtf((tx0 - px0) * (tx0 - px0) + (ty0 - py0) * (ty0 - py0));
        const float ed1 = sqrtf((tx1 - px1) * (tx1 - px1) + (ty1 - py1) * (ty1 - py1));

        const float pvx = px0 - px1, pvy = py0 - py1;
        const float tvx = tx0 - tx1, tvy = ty0 - ty1;
        const float pd = sqrtf(pvx * pvx + pvy * pvy);
        const float td = sqrtf(tvx * tvx + tvy * tvy);
        const float dot = pvx * tvx + pvy * tvy;
        const float cosd = 1.0f - cosf(dot / (pd * td));
        term = ed0 + ed1 + fabsf(pd - td) + cosd;
    }

#pragma unroll
    for (int off = 32; off > 0; off >>= 1)
        term += __shfl_down(term, off, 64);
    const int lane = tid & 63, wid = tid >> 6;
    if (lane == 0) wsum[wid] = term;
    __syncthreads();
    if (tid == 0) out[0] = (wsum[0] + wsum[1]) * (1.0f / 64.0f);
}

extern "C" void kernel_launch(void* const* d_in, const int* in_sizes, int n_in,
                              void* d_out, int out_size, void* d_ws, size_t ws_size,
                              hipStream_t stream)
{
    const float* inp = (const float*)d_in[0];
    const float* tgt = (const float*)d_in[1];
    float* out = (float*)d_out;
    float* wsf = (float*)d_ws;
    int*   wsi = (int*)((float*)d_ws + 4 * NPART2);

    dsnt_partial<<<2 * NPART2, 256, 0, stream>>>(inp, tgt, wsf, wsi);
    dsnt_finalize<<<1, 128, 0, stream>>>(wsf, wsi, out);
}

// Round 6
// 259.553 us; speedup vs baseline: 1.0012x; 1.0012x over previous
//
#include <hip/hip_runtime.h>
#include <math.h>

// Problem constants (B=64, P=2, H=512, W=512)
#define HH 512
#define WW 512
#define BP 128                  // B*P pairs
#define PLANE (HH * WW)         // 262144 elems per (b,p) plane
#define SEG2 32                 // segments per pair
#define SEG_FLOATS 8192         // floats per segment (32 KB)
#define NPART2 (BP * SEG2)      // 4096 partial records per quantity
#define CHUNK_F 1024            // floats per pipeline chunk (4 KB)
#define NCHUNK 8                // chunks per segment

// ws float layout: [0,4096) sum, [4096,8192) sumx, [8192,12288) sumy,
// [12288,16384) maxval ; ints at float offset [16384,20480) maxidx. 80 KiB.

// R10: NT + deep DMA pipeline. Evidence so far: NT loads (R8) broke the
// 2.7 TB/s Infinity-Cache-allocate wall (99 -> 77 us) but reg-path depth
// did nothing (R9 == R8), and the allocator has sabotaged every >2-deep
// register rotation (R4/R5/R9). The DMA path (R7) verifiably holds 8
// loads/wave in flight (no data VGPRs, allocator can't serialize) but
// lacked NT and pinned at the IC wall. This round combines them: R7's
// persistent per-wave double-buffered LDS streamer with aux=2 (NT CPol bit,
// same bit __builtin_nontemporal_load sets) on every global_load_lds.
// If request depth was the post-NT limiter: ~45-55 us. If unchanged: NT
// read service ~3.5 TB/s is the cap -> roofline.
__device__ __forceinline__ void gload_lds16_nt(const float* g, float* l)
{
    __builtin_amdgcn_global_load_lds(
        (const __attribute__((address_space(1))) void*)g,
        (__attribute__((address_space(3))) void*)l, 16, 0, /*aux=NT*/ 2);
}

// Issue one 4 KB chunk: 4 DMA loads of 1 KB (64 lanes x 16 B).
// LDS dest wave-uniform + lane*16 (HW requirement); global src per-lane.
__device__ __forceinline__ void issue_chunk(const float* gsrc, float* ldst,
                                            int lane)
{
#pragma unroll
    for (int ld = 0; ld < 4; ++ld)
        gload_lds16_nt(gsrc + ld * 256 + lane * 4, ldst + ld * 256);
}

__global__ __launch_bounds__(256) void dsnt_partial(
    const float* __restrict__ inp, const float* __restrict__ tgt,
    float* __restrict__ wsf, int* __restrict__ wsi)
{
    const int tid  = threadIdx.x;
    const int lane = tid & 63, wid = tid >> 6;
    const float inv = 1.0f / 512.0f;

    __shared__ float lds[4][2][CHUNK_F];   // per-wave double buffer, 32 KB

    const int  g     = blockIdx.x * 4 + wid;   // segment id 0..8191
    const bool is_sm = (g < NPART2);
    const int  b2    = is_sm ? g : g - NPART2;
    const int  pair  = b2 >> 5;
    const int  seg   = b2 & 31;
    const float* __restrict__ gbase =
        (is_sm ? inp : tgt) + (size_t)pair * PLANE + seg * SEG_FLOATS;
    const int segbase = seg * SEG_FLOATS;

    float* const bufA = &lds[wid][0][0];
    float* const bufB = &lds[wid][1][0];

    // Prologue: fill both buffers' requests (8 loads in flight).
    issue_chunk(gbase + 0 * CHUNK_F, bufA, lane);
    issue_chunk(gbase + 1 * CHUNK_F, bufB, lane);

    if (is_sm) {
        // ---- softmax partial sums ----
        float s = 0.0f, sx = 0.0f, sy = 0.0f;
#pragma unroll
        for (int c = 0; c < NCHUNK; ++c) {
            float* const buf = (c & 1) ? bufB : bufA;
            // Counted wait: chunk c landed, next chunk's 4 loads still flying.
            if (c < NCHUNK - 1)
                asm volatile("s_waitcnt vmcnt(4)" ::: "memory");
            else
                asm volatile("s_waitcnt vmcnt(0)" ::: "memory");
            const float4* const lp = (const float4*)buf;
#pragma unroll
            for (int i = 0; i < 4; ++i) {
                const float4 v = lp[i * 64 + lane];
                const int f = segbase + c * CHUNK_F + (i * 64 + lane) * 4;
                const float yw  = (float)((f >> 9) + 1) * inv;
                const float xw0 = (float)((f & 511) + 1) * inv;
                const float e0 = __expf(v.x);
                const float e1 = __expf(v.y);
                const float e2 = __expf(v.z);
                const float e3 = __expf(v.w);
                const float es = e0 + e1 + e2 + e3;
                s  += es;
                sx += es * xw0 + inv * (e1 + 2.0f * e2 + 3.0f * e3);
                sy += es * yw;
            }
            if (c + 2 < NCHUNK) {
                // All ds_reads of this buffer done before DMA overwrites it.
                asm volatile("s_waitcnt lgkmcnt(0)" ::: "memory");
                issue_chunk(gbase + (c + 2) * CHUNK_F, buf, lane);
            }
        }

#pragma unroll
        for (int off = 32; off > 0; off >>= 1) {
            s  += __shfl_down(s,  off, 64);
            sx += __shfl_down(sx, off, 64);
            sy += __shfl_down(sy, off, 64);
        }
        if (lane == 0) {
            wsf[g]              = s;
            wsf[NPART2 + g]     = sx;
            wsf[2 * NPART2 + g] = sy;
        }
    } else {
        // ---- argmax partial over target ----
        float mv = -1.0f;
        int   mi = 0;
#pragma unroll
        for (int c = 0; c < NCHUNK; ++c) {
            float* const buf = (c & 1) ? bufB : bufA;
            if (c < NCHUNK - 1)
                asm volatile("s_waitcnt vmcnt(4)" ::: "memory");
            else
                asm volatile("s_waitcnt vmcnt(0)" ::: "memory");
            const float4* const lp = (const float4*)buf;
#pragma unroll
            for (int i = 0; i < 4; ++i) {
                const float4 v = lp[i * 64 + lane];
                const int f = segbase + c * CHUNK_F + (i * 64 + lane) * 4;
                if (v.x > mv) { mv = v.x; mi = f; }
                if (v.y > mv) { mv = v.y; mi = f + 1; }
                if (v.z > mv) { mv = v.z; mi = f + 2; }
                if (v.w > mv) { mv = v.w; mi = f + 3; }
            }
            if (c + 2 < NCHUNK) {
                asm volatile("s_waitcnt lgkmcnt(0)" ::: "memory");
                issue_chunk(gbase + (c + 2) * CHUNK_F, buf, lane);
            }
        }

#pragma unroll
        for (int off = 32; off > 0; off >>= 1) {
            const float ov = __shfl_down(mv, off, 64);
            const int   oi = __shfl_down(mi, off, 64);
            if (ov > mv || (ov == mv && oi < mi)) { mv = ov; mi = oi; }
        }
        if (lane == 0) {
            wsf[3 * NPART2 + b2] = mv;
            wsi[b2]              = mi;
        }
    }
}

__global__ __launch_bounds__(128) void dsnt_finalize(
    const float* __restrict__ wsf, const int* __restrict__ wsi,
    float* __restrict__ out)
{
    __shared__ float px[BP], py[BP], tx[BP], ty[BP];
    __shared__ float wsum[2];
    const int tid = threadIdx.x; // 0..127, one pair per thread

    {
        float s = 0.0f, sx = 0.0f, sy = 0.0f, mv = -1.0f;
        int mi = 0;
#pragma unroll
        for (int k = 0; k < SEG2; ++k) {
            const int i = tid * SEG2 + k;  // segs in ascending index order
            s  += wsf[i];
            sx += wsf[NPART2 + i];
            sy += wsf[2 * NPART2 + i];
            const float v = wsf[3 * NPART2 + i];
            const int  ii = wsi[i];
            if (v > mv || (v == mv && ii < mi)) { mv = v; mi = ii; }
        }
        px[tid] = sx / s;
        py[tid] = sy / s;
        tx[tid] = (float)((mi & 511) + 1) * (1.0f / 512.0f);
        ty[tid] = (float)((mi >> 9) + 1) * (1.0f / 512.0f);
    }
    __syncthreads();

    float term = 0.0f;
    if (tid < 64) {
        const int b = tid;
        const float px0 = px[2 * b], px1 = px[2 * b + 1];
        const float py0 = py[2 * b], py1 = py[2 * b + 1];
        const float tx0 = tx[2 * b], tx1 = tx[2 * b + 1];
        const float ty0 = ty[2 * b], ty1 = ty[2 * b + 1];

        const float ed0 = sqrtf((tx0 - px0) * (tx0 - px0) + (ty0 - py0) * (ty0 - py0));
        const float ed1 = sqrtf((tx1 - px1) * (tx1 - px1) + (ty1 - py1) * (ty1 - py1));

        const float pvx = px0 - px1, pvy = py0 - py1;
        const float tvx = tx0 - tx1, tvy = ty0 - ty1;
        const float pd = sqrtf(pvx * pvx + pvy * pvy);
        const float td = sqrtf(tvx * tvx + tvy * tvy);
        const float dot = pvx * tvx + pvy * tvy;
        const float cosd = 1.0f - cosf(dot / (pd * td));
        term = ed0 + ed1 + fabsf(pd - td) + cosd;
    }

#pragma unroll
    for (int off = 32; off > 0; off >>= 1)
        term += __shfl_down(term, off, 64);
    const int lane = tid & 63, wid = tid >> 6;
    if (lane == 0) wsum[wid] = term;
    __syncthreads();
    if (tid == 0) out[0] = (wsum[0] + wsum[1]) * (1.0f / 64.0f);
}

extern "C" void kernel_launch(void* const* d_in, const int* in_sizes, int n_in,
                              void* d_out, int out_size, void* d_ws, size_t ws_size,
                              hipStream_t stream)
{
    const float* inp = (const float*)d_in[0];
    const float* tgt = (const float*)d_in[1];
    float* out = (float*)d_out;
    float* wsf = (float*)d_ws;
    int*   wsi = (int*)((float*)d_ws + 4 * NPART2);

    dsnt_partial<<<2048, 256, 0, stream>>>(inp, tgt, wsf, wsi);
    dsnt_finalize<<<1, 128, 0, stream>>>(wsf, wsi, out);
}